// Round 5
// baseline (660.468 us; speedup 1.0000x reference)
//
#include <hip/hip_runtime.h>
#include <math.h>

#define B_  128
#define C_  512
#define S_  128
#define M_  512
#define BN_EPS 1e-5f

typedef __attribute__((ext_vector_type(8))) short   short8;
typedef __attribute__((ext_vector_type(4))) float   floatx4;
typedef __attribute__((ext_vector_type(4))) unsigned short ushort4v;
typedef __attribute__((ext_vector_type(8))) unsigned short ushort8v;

// fp32 -> bf16 bits, round-to-nearest-even (finite inputs)
__device__ __forceinline__ unsigned short f2bu(float f) {
    union { float f; unsigned int u; } c; c.f = f;
    unsigned int u = c.u;
    return (unsigned short)((u + 0x7fffu + ((u >> 16) & 1u)) >> 16);
}

// ---------------------------------------------------------------------------
// fp32 -> bf16, 8 elems/thread, 4 weight matrices (each M_*S_ elems).
// ---------------------------------------------------------------------------
__global__ __launch_bounds__(256)
void f2bf4_kernel(const float* __restrict__ a0, const float* __restrict__ a1,
                  const float* __restrict__ a2, const float* __restrict__ a3,
                  unsigned short* __restrict__ out, long n8)
{
    const float* in = (blockIdx.y == 0) ? a0 : (blockIdx.y == 1) ? a1
                    : (blockIdx.y == 2) ? a2 : a3;
    unsigned short* o = out + (long)blockIdx.y * (n8 * 8);
    const long i = (long)blockIdx.x * 256 + threadIdx.x;
    if (i >= n8) return;
    const float4* p = (const float4*)in + 2 * i;
    const float4 x = p[0], y = p[1];
    ushort4v u0, u1;
    u0.x = f2bu(x.x); u0.y = f2bu(x.y); u0.z = f2bu(x.z); u0.w = f2bu(x.w);
    u1.x = f2bu(y.x); u1.y = f2bu(y.y); u1.z = f2bu(y.z); u1.w = f2bu(y.w);
    ((ushort4v*)o)[2 * i]     = u0;
    ((ushort4v*)o)[2 * i + 1] = u1;
}

// ---------------------------------------------------------------------------
// Pack bq/bk/bv contiguous ([3][512]) and zero the BN stats accumulators.
// ---------------------------------------------------------------------------
__global__ __launch_bounds__(256)
void pack_bias_zero_stats(const float* __restrict__ bq, const float* __restrict__ bk,
                          const float* __restrict__ bv, float* __restrict__ bqkv,
                          float* __restrict__ stats)
{
    const int t = blockIdx.x * 256 + threadIdx.x;
    if (t < 512)            bqkv[t] = bq[t];
    else if (t < 1024)      bqkv[t] = bk[t - 512];
    else if (t < 1536)      bqkv[t] = bv[t - 1024];
    else if (t < 1536 + 2 * C_) stats[t - 1536] = 0.f;
}

// ---------------------------------------------------------------------------
// Barrier-free projection: NO LDS, fragments loaded per-lane from global.
// Block = 64-row strip x all 512 cols, 8 waves 1x8 (wave w -> cols w*64..).
// Wave tile 64x64 = acc[4][4]. A (fp32) fragments converted in-loop; A
// strip-chunk (8 KB/step) is L1-resident across the 8 waves; W (bf16,
// 128 KB/tensor) is L2-resident. Zero __syncthreads in the whole kernel ->
// compiler emits counted per-use vmcnt, waves pipeline independently.
// Output: scalar ushort stores (16 lanes -> 32 B segments; WRITE_SIZE exact
// per r2 measurement).
// ---------------------------------------------------------------------------
__global__ __launch_bounds__(512, 2)
void proj_kernel(const float* __restrict__ qf, const float* __restrict__ kf,
                 const float* __restrict__ vf, const unsigned short* __restrict__ Wbf,
                 const float* __restrict__ bqkv, unsigned short* __restrict__ outbf)
{
    const int z     = blockIdx.y;     // tensor 0..2
    const int strip = blockIdx.x;     // 0..1023
    const float* A = (z == 0 ? qf : z == 1 ? kf : vf) + (long)strip * 64 * S_;
    const unsigned short* W = Wbf + (long)z * M_ * S_;
    unsigned short* O = outbf + (long)z * ((long)B_ * C_ * M_) + (long)strip * 64 * M_;

    const int lane = threadIdx.x & 63;
    const int wave = threadIdx.x >> 6;    // 0..7
    const int lrow = lane & 15;
    const int quad = lane >> 4;
    const int cb   = wave * 64;

    floatx4 acc[4][4] = {};

    #pragma unroll
    for (int c = 0; c < 4; ++c) {         // K chunks of 32
        short8 af[4], bfr[4];
        #pragma unroll
        for (int i = 0; i < 4; ++i) {
            const float* ap = A + (long)(i * 16 + lrow) * S_ + c * 32 + quad * 8;
            const float4 a0 = *(const float4*)ap;
            const float4 a1 = *(const float4*)(ap + 4);
            short8 v;
            v[0] = f2bu(a0.x); v[1] = f2bu(a0.y); v[2] = f2bu(a0.z); v[3] = f2bu(a0.w);
            v[4] = f2bu(a1.x); v[5] = f2bu(a1.y); v[6] = f2bu(a1.z); v[7] = f2bu(a1.w);
            af[i] = v;
        }
        #pragma unroll
        for (int j = 0; j < 4; ++j)
            bfr[j] = *(const short8*)(W + (long)(cb + j * 16 + lrow) * S_ + c * 32 + quad * 8);
        #pragma unroll
        for (int i = 0; i < 4; ++i)
            #pragma unroll
            for (int j = 0; j < 4; ++j)
                acc[i][j] = __builtin_amdgcn_mfma_f32_16x16x32_bf16(
                    af[i], bfr[j], acc[i][j], 0, 0, 0);
    }

    // epilogue: bias + scalar bf16 stores (C/D: col=j*16+lrow, row=quad*4+rg)
    #pragma unroll
    for (int j = 0; j < 4; ++j) {
        const int col = cb + j * 16 + lrow;
        const float bv = bqkv[z * M_ + col];
        #pragma unroll
        for (int i = 0; i < 4; ++i)
            #pragma unroll
            for (int rg = 0; rg < 4; ++rg)
                O[(long)(i * 16 + quad * 4 + rg) * M_ + col] = f2bu(acc[i][j][rg] + bv);
    }
}

// ---------------------------------------------------------------------------
// bf16 MFMA GEMM, NT form: C[i,j] = scale * sum_k A[i,k]*Bm[j,k] (+ bias[j])
//   Batched over blockIdx.z with element strides sA/sB/sC/sBias.
//   outMode 0: fp32 C [ldC];  1: bf16 C [ldC];
//           2: bf16 scattered vwT: addr = (r>>9)*65536 + col*512 + (r&511)
//   STATS: accumulate per-row sum/sumsq of fp32 output into statsOut (atomics).
// ---------------------------------------------------------------------------
template<bool STATS>
__global__ __launch_bounds__(256)
void gemm_bf16(const unsigned short* __restrict__ A, const unsigned short* __restrict__ Bm,
               const float* __restrict__ bias, void* __restrict__ Cc,
               int M, int N, int K, int ldA, int ldB, int ldC,
               long sA, long sB, long sC, long sBias, float scale, int outMode,
               float* __restrict__ statsOut)
{
    const int bz = blockIdx.z;
    A  += (long)bz * sA;
    Bm += (long)bz * sB;
    if (bias) bias += (long)bz * sBias;

    __shared__ unsigned short As[128][72];
    __shared__ unsigned short Bs[128][72];

    const int t    = threadIdx.x;
    const int lane = t & 63;
    const int wave = t >> 6;
    const int wm   = (wave >> 1) * 64;
    const int wn   = (wave & 1) * 64;
    const int lrow = lane & 15;
    const int quad = lane >> 4;
    const int row0 = blockIdx.x * 128;
    const int col0 = blockIdx.y * 128;

    floatx4 acc[4][4] = {};

    const int srow = t >> 3;
    const int skc  = (t & 7) * 8;

    for (int k0 = 0; k0 < K; k0 += 64) {
        #pragma unroll
        for (int i = 0; i < 4; ++i) {
            const int r = srow + i * 32;
            *(short8*)&As[r][skc] =
                *(const short8*)(A + (long)(row0 + r) * ldA + k0 + skc);
            *(short8*)&Bs[r][skc] =
                *(const short8*)(Bm + (long)(col0 + r) * ldB + k0 + skc);
        }
        __syncthreads();

        #pragma unroll
        for (int kb = 0; kb < 2; ++kb) {
            short8 af[4], bfr[4];
            #pragma unroll
            for (int i = 0; i < 4; ++i)
                af[i]  = *(const short8*)&As[wm + i * 16 + lrow][kb * 32 + quad * 8];
            #pragma unroll
            for (int j = 0; j < 4; ++j)
                bfr[j] = *(const short8*)&Bs[wn + j * 16 + lrow][kb * 32 + quad * 8];
            #pragma unroll
            for (int i = 0; i < 4; ++i)
                #pragma unroll
                for (int j = 0; j < 4; ++j)
                    acc[i][j] = __builtin_amdgcn_mfma_f32_16x16x32_bf16(
                        af[i], bfr[j], acc[i][j], 0, 0, 0);
        }
        __syncthreads();
    }

    float rs[4][4], rss[4][4];
    if (STATS) {
        #pragma unroll
        for (int i = 0; i < 4; ++i)
            #pragma unroll
            for (int rg = 0; rg < 4; ++rg) { rs[i][rg] = 0.f; rss[i][rg] = 0.f; }
    }
    #pragma unroll
    for (int j = 0; j < 4; ++j) {
        const int col = col0 + wn + j * 16 + lrow;
        const float bv = bias ? bias[col] : 0.0f;
        #pragma unroll
        for (int i = 0; i < 4; ++i) {
            const int rbase = row0 + wm + i * 16 + quad * 4;
            #pragma unroll
            for (int reg = 0; reg < 4; ++reg) {
                const float val = acc[i][j][reg] * scale + bv;
                const int r = rbase + reg;
                if (STATS) { rs[i][reg] += val; rss[i][reg] += val * val; }
                if (outMode == 0) {
                    ((float*)Cc)[(long)bz * sC + (long)r * ldC + col] = val;
                } else if (outMode == 1) {
                    ((unsigned short*)Cc)[(long)bz * sC + (long)r * ldC + col] = f2bu(val);
                } else {
                    ((unsigned short*)Cc)[((long)(r >> 9)) * 65536 + (long)col * 512 + (r & 511)] = f2bu(val);
                }
            }
        }
    }
    if (STATS) {
        #pragma unroll
        for (int i = 0; i < 4; ++i) {
            #pragma unroll
            for (int reg = 0; reg < 4; ++reg) {
                float s = rs[i][reg], ss = rss[i][reg];
                #pragma unroll
                for (int off = 1; off < 16; off <<= 1) {
                    s  += __shfl_xor(s,  off);
                    ss += __shfl_xor(ss, off);
                }
                if (lrow == 0) {
                    const int r = row0 + wm + i * 16 + quad * 4 + reg;
                    atomicAdd(&statsOut[r],      s);
                    atomicAdd(&statsOut[C_ + r], ss);
                }
            }
        }
    }
}

// ---------------------------------------------------------------------------
// Barrier-free fused scores + softmax. Block = 64 rows x 512 cols, one batch.
// 8 waves (wave w -> cols w*64..); q/k fragments loaded per-lane from global
// (L2-resident, XCD-swizzled). NO LDS in the MFMA loop -> no barriers ->
// compiler pipelines loads across K-steps with counted vmcnt.
// LDS only for cross-wave softmax reduction + per-wave output bounce.
// ---------------------------------------------------------------------------
__global__ __launch_bounds__(512, 2)
void scores_softmax_kernel(const unsigned short* __restrict__ q_bf,
                           const unsigned short* __restrict__ k_bf,
                           float* __restrict__ attn,
                           unsigned short* __restrict__ attnbf,
                           float scale)
{
    const int bid = blockIdx.x;
    const int b   = (bid & 7) * 16 + (bid >> 6);          // batch 0..127
    const int r0  = ((bid >> 3) & 7) * 64;                // row strip

    const unsigned short* qg = q_bf + (long)b * C_ * M_;
    const unsigned short* kg = k_bf + (long)b * C_ * M_;
    float* ab           = attn   + (long)b * C_ * C_;
    unsigned short* abf = attnbf + (long)b * C_ * C_;

    __shared__ float red[64][9];
    __shared__ float scr[8][16][68];     // per-wave epilogue bounce

    const int t    = threadIdx.x;
    const int lane = t & 63;
    const int wave = t >> 6;          // 0..7
    const int lrow = lane & 15;
    const int quad = lane >> 4;
    const int cb   = wave * 64;

    floatx4 acc[4][4] = {};

    const unsigned short* qbase = qg + (long)(r0 + lrow) * M_ + quad * 8;
    const unsigned short* kbase = kg + (long)(cb + lrow) * M_ + quad * 8;

    #pragma unroll 2
    for (int k0 = 0; k0 < M_; k0 += 32) {
        short8 af[4], bfr[4];
        #pragma unroll
        for (int i = 0; i < 4; ++i)
            af[i]  = *(const short8*)(qbase + (long)i * 16 * M_ + k0);
        #pragma unroll
        for (int j = 0; j < 4; ++j)
            bfr[j] = *(const short8*)(kbase + (long)j * 16 * M_ + k0);
        #pragma unroll
        for (int i = 0; i < 4; ++i)
            #pragma unroll
            for (int j = 0; j < 4; ++j)
                acc[i][j] = __builtin_amdgcn_mfma_f32_16x16x32_bf16(
                    af[i], bfr[j], acc[i][j], 0, 0, 0);
    }

    // ---- row max: per-lane over 4 col-tiles, 16-lane shfl, cross-wave via red
    float mx[4][4];
    #pragma unroll
    for (int i = 0; i < 4; ++i) {
        #pragma unroll
        for (int rg = 0; rg < 4; ++rg) {
            float m = fmaxf(fmaxf(acc[i][0][rg], acc[i][1][rg]),
                            fmaxf(acc[i][2][rg], acc[i][3][rg]));
            #pragma unroll
            for (int off = 1; off < 16; off <<= 1) m = fmaxf(m, __shfl_xor(m, off));
            mx[i][rg] = m;
        }
    }
    if (lrow == 0) {
        #pragma unroll
        for (int i = 0; i < 4; ++i)
            #pragma unroll
            for (int rg = 0; rg < 4; ++rg)
                red[i * 16 + quad * 4 + rg][wave] = mx[i][rg];
    }
    __syncthreads();
    #pragma unroll
    for (int i = 0; i < 4; ++i) {
        #pragma unroll
        for (int rg = 0; rg < 4; ++rg) {
            const int row = i * 16 + quad * 4 + rg;
            float m = red[row][0];
            #pragma unroll
            for (int w = 1; w < 8; ++w) m = fmaxf(m, red[row][w]);
            mx[i][rg] = m;
        }
    }
    __syncthreads();   // red reused for sums

    // ---- exp (scale folded) + row sum
    float sm[4][4];
    #pragma unroll
    for (int i = 0; i < 4; ++i) {
        #pragma unroll
        for (int rg = 0; rg < 4; ++rg) {
            float s = 0.f;
            #pragma unroll
            for (int j = 0; j < 4; ++j) {
                const float e = __expf((acc[i][j][rg] - mx[i][rg]) * scale);
                acc[i][j][rg] = e;
                s += e;
            }
            #pragma unroll
            for (int off = 1; off < 16; off <<= 1) s += __shfl_xor(s, off);
            sm[i][rg] = s;
        }
    }
    if (lrow == 0) {
        #pragma unroll
        for (int i = 0; i < 4; ++i)
            #pragma unroll
            for (int rg = 0; rg < 4; ++rg)
                red[i * 16 + quad * 4 + rg][wave] = sm[i][rg];
    }
    __syncthreads();
    #pragma unroll
    for (int i = 0; i < 4; ++i) {
        #pragma unroll
        for (int rg = 0; rg < 4; ++rg) {
            const int row = i * 16 + quad * 4 + rg;
            float s = red[row][0];
            #pragma unroll
            for (int w = 1; w < 8; ++w) s += red[row][w];
            sm[i][rg] = 1.0f / s;
        }
    }

    // ---- write phase: per-wave LDS bounce (within-wave only, no barrier)
    float* sw = &scr[wave][0][0];       // 16x68 fp32
    const int rr = lane >> 3;
    const int rc = (lane & 7) * 4;
    #pragma unroll
    for (int i = 0; i < 4; ++i) {
        #pragma unroll
        for (int j = 0; j < 4; ++j)
            #pragma unroll
            for (int rg = 0; rg < 4; ++rg)
                sw[(quad * 4 + rg) * 68 + j * 16 + lrow] = acc[i][j][rg] * sm[i][rg];
        #pragma unroll
        for (int pr = 0; pr < 2; ++pr) {
            #pragma unroll
            for (int pc = 0; pc < 2; ++pc) {
                const int row = pr * 8 + rr;
                const int col = pc * 32 + rc;
                const float4 v = *(const float4*)&sw[row * 68 + col];
                const long gr = r0 + i * 16 + row;
                const long gc = cb + col;
                *(float4*)&ab[gr * C_ + gc] = v;
                ushort4v u;
                u.x = f2bu(v.x); u.y = f2bu(v.y); u.z = f2bu(v.z); u.w = f2bu(v.w);
                *(ushort4v*)&abf[gr * C_ + gc] = u;
            }
        }
    }
}

// ---------------------------------------------------------------------------
// BN + ReLU + residual; finalizes mean/istd from raw atomic sums inline.
// ---------------------------------------------------------------------------
__global__ __launch_bounds__(256)
void bn_apply_kernel(const float* __restrict__ outp, const float* __restrict__ value,
                     const float* __restrict__ stats, const float* __restrict__ gamma,
                     const float* __restrict__ beta, float* __restrict__ out)
{
    const long i4 = (long)blockIdx.x * 256 + threadIdx.x;
    const int  c  = (int)((i4 >> 5) & (C_ - 1));

    const float invn = 1.0f / (float)(B_ * S_);
    const float mean = stats[c] * invn;
    const float var  = stats[C_ + c] * invn - mean * mean;
    const float istd = rsqrtf(var + BN_EPS);
    const float g    = gamma[c] * istd;
    const float bc   = beta[c] - mean * g;

    const float4 x = ((const float4*)outp)[i4];
    const float4 r = ((const float4*)value)[i4];
    float4 y;
    y.x = fmaxf(fmaf(x.x, g, bc), 0.f) + r.x;
    y.y = fmaxf(fmaf(x.y, g, bc), 0.f) + r.y;
    y.z = fmaxf(fmaf(x.z, g, bc), 0.f) + r.z;
    y.w = fmaxf(fmaf(x.w, g, bc), 0.f) + r.w;
    ((float4*)out)[i4] = y;
}

// ---------------------------------------------------------------------------
extern "C" void kernel_launch(void* const* d_in, const int* in_sizes, int n_in,
                              void* d_out, int out_size, void* d_ws, size_t ws_size,
                              hipStream_t stream)
{
    const float* query = (const float*)d_in[0];
    const float* key   = (const float*)d_in[1];
    const float* value = (const float*)d_in[2];
    const float* Wq    = (const float*)d_in[3];
    const float* bq    = (const float*)d_in[4];
    const float* Wk    = (const float*)d_in[5];
    const float* bk    = (const float*)d_in[6];
    const float* Wv    = (const float*)d_in[7];
    const float* bv    = (const float*)d_in[8];
    const float* Wf    = (const float*)d_in[9];
    const float* bf    = (const float*)d_in[10];
    const float* gamma = (const float*)d_in[11];
    const float* beta  = (const float*)d_in[12];

    const long BC  = (long)B_ * C_;       // 65536
    const long BCM = BC * M_;             // 33,554,432
    const long BCS = BC * S_;             //  8,388,608
    const long BCC = BC * C_;             // 33,554,432

    // ---- workspace carve (bf16 = ushort). All offsets 16B-aligned.
    unsigned short* w      = (unsigned short*)d_ws;
    unsigned short* q_bf   = w;                     // [BC, M] (q,k,v contiguous)
    unsigned short* k_bf   = q_bf + BCM;
    unsigned short* v2_bf  = k_bf + BCM;
    unsigned short* attnbf = v2_bf + BCM;           // [B, C, C]
    unsigned short* vwT    = attnbf + BCC;          // [B, S, C]
    unsigned short* Wq_bf  = vwT + (long)B_ * S_ * C_;  // [M,S]x3 then Wf [S,M]
    unsigned short* Wf_bf  = Wq_bf + 3L * M_ * S_;
    float* outp  = (float*)(Wf_bf + (long)S_ * M_); // [BC, S] fp32
    float* stats = outp + BCS;                      // [2*C] raw sums (atomics)
    // packed biases at head of attnbf (dead until scores kernel runs)
    float* bqkv = (float*)attnbf;                   // [3][512]

    float* out0 = (float*)d_out;          // [B, C, S]
    float* attn = out0 + BCS;             // [B, C, C]

    const float scale = 1.0f / sqrtf((float)M_);
    dim3 blk(256);
    dim3 blk512(512);

    // 0. weight conversions + bias pack / stats zero
    f2bf4_kernel<<<dim3(32, 4), blk, 0, stream>>>(Wq, Wk, Wv, Wf, Wq_bf,
                                                  (long)M_ * S_ / 8);
    pack_bias_zero_stats<<<dim3(10), blk, 0, stream>>>(bq, bk, bv, bqkv, stats);

    // 1. q/k/v projections: barrier-free, fragments direct from L1/L2
    proj_kernel<<<dim3(1024, 3), blk512, 0, stream>>>(
        query, key, value, Wq_bf, bqkv, q_bf);

    // 2+3. fused scores + softmax: fp32 attn (output 2) + bf16 copy
    scores_softmax_kernel<<<dim3(1024), blk512, 0, stream>>>(
        q_bf, k_bf, attn, attnbf, scale);

    // 4. vw = v2 @ Wf^T + bf -> bf16, stored TRANSPOSED as vwT[b][s][c]
    //    (bias fold exact: softmax rows sum to 1)
    gemm_bf16<false><<<dim3(512, 1, 1), blk, 0, stream>>>(
        v2_bf, Wf_bf, bf, vwT, (int)BC, S_, M_, M_, M_, 0,
        0, 0, 0, 0, 1.0f, 2, nullptr);

    // 5. outp = attn @ vw (NT via vwT) + fused BN partial sums via atomics
    gemm_bf16<true><<<dim3(4, 1, 128), blk, 0, stream>>>(
        attnbf, vwT, nullptr, outp, C_, S_, C_, C_, C_, S_,
        (long)C_ * C_, (long)S_ * C_, (long)C_ * S_, 0, 1.0f, 0, stats);

    // 6. BN finalize + ReLU + residual -> out0
    bn_apply_kernel<<<dim3(BCS / 4 / 256), blk, 0, stream>>>(
        outp, value, stats, gamma, beta, out0);
}